// Round 6
// baseline (89.453 us; speedup 1.0000x reference)
//
#include <hip/hip_runtime.h>

// Npool: soft max-pool along last axis.
// x: (8,32,64,4096) f32 -> out: (8,32,64,2047) f32, window=4, stride=2, nn=1.
// Per window: mi = first-argmax. mi in {0,3} -> out = max (eff=0).
//             mi in {1,2} -> out = 0.25*win[mi-1] + 0.5*win[mi] + 0.25*win[mi+1].
//
// R6 = R5 with clang-native vector type for the nontemporal builtins
// (HIP_vector_type struct is rejected; ext_vector_type is accepted).
// Persistent grid-stride (2048 blocks = 8/CU), nontemporal loads+stores,
// wave processes segment pairs: 2 dense float4 loads/lane; pair-internal
// edge via broadcast shuffle from segment B's lane 0.

#define ROW_W 4096
#define OUT_W 2047

typedef float fvec4 __attribute__((ext_vector_type(4)));

__device__ __forceinline__ float pool4(float w0, float w1, float w2, float w3) {
    int mi = 0; float m = w0;
    if (w1 > m) { m = w1; mi = 1; }
    if (w2 > m) { m = w2; mi = 2; }
    if (w3 > m) { m = w3; mi = 3; }
    const float lo = (mi == 1) ? w0 : w1;
    const float hi = (mi == 1) ? w2 : w3;
    const float interior = 0.25f * lo + 0.5f * m + 0.25f * hi;
    return (mi == 0 || mi == 3) ? m : interior;
}

__global__ __launch_bounds__(256) void npool_kernel(const float* __restrict__ x,
                                                    float* __restrict__ out,
                                                    int npairs) {
    const int lane = threadIdx.x & 63;
    const int gw   = (blockIdx.x * 256 + threadIdx.x) >> 6;   // global wave id
    const int nw   = (gridDim.x * 256) >> 6;                  // total waves (8192)

    for (int sp = gw; sp < npairs; sp += nw) {
        const int s0  = sp << 1;          // even segment index
        const int row = s0 >> 4;          // 16 segments per row
        const int seg = s0 & 15;          // 0,2,...,14
        const float* rx = x + (size_t)row * ROW_W + (seg << 8);
        float*       ro = out + (size_t)row * OUT_W + (seg << 7);

        // Dense 16B-stride loads: segment A and B of the pair.
        const fvec4 v1 = __builtin_nontemporal_load(reinterpret_cast<const fvec4*>(rx) + lane);
        const fvec4 v2 = __builtin_nontemporal_load(reinterpret_cast<const fvec4*>(rx + 256) + lane);

        float e0 = 0.f, e1 = 0.f;
        if (lane == 63) {                 // edge pair for segment B's last output
            const float* ep = rx + ((seg == 14) ? 510 : 512);  // clamp: value unused (masked)
            e0 = ep[0]; e1 = ep[1];
        }

        // Segment A: neighbor pair from next lane; lane 63 from lane 0 of v2.
        const float b0 = __shfl(v2.x, 0, 64);
        const float b1 = __shfl(v2.y, 0, 64);
        float n0 = __shfl_down(v1.x, 1, 64);
        float n1 = __shfl_down(v1.y, 1, 64);
        if (lane == 63) { n0 = b0; n1 = b1; }

        const float rA0 = pool4(v1.x, v1.y, v1.z, v1.w);
        const float rA1 = pool4(v1.z, v1.w, n0, n1);

        // Segment B: lane 63 from the edge load.
        float m0 = __shfl_down(v2.x, 1, 64);
        float m1 = __shfl_down(v2.y, 1, 64);
        if (lane == 63) { m0 = e0; m1 = e1; }

        const float rB0 = pool4(v2.x, v2.y, v2.z, v2.w);
        const float rB1 = pool4(v2.z, v2.w, m0, m1);

        const int oA = 2 * lane;
        __builtin_nontemporal_store(rA0, ro + oA);
        __builtin_nontemporal_store(rA1, ro + oA + 1);
        const int oB = 128 + 2 * lane;
        __builtin_nontemporal_store(rB0, ro + oB);
        if (!(seg == 14 && lane == 63))                  // o=2047 doesn't exist
            __builtin_nontemporal_store(rB1, ro + oB + 1);
    }
}

extern "C" void kernel_launch(void* const* d_in, const int* in_sizes, int n_in,
                              void* d_out, int out_size, void* d_ws, size_t ws_size,
                              hipStream_t stream) {
    const float* x = (const float*)d_in[0];
    float* out = (float*)d_out;

    const int rows   = in_sizes[0] / ROW_W;   // 16384
    const int npairs = rows * 8;              // 2 segments per pair, 16 seg/row
    npool_kernel<<<2048, 256, 0, stream>>>(x, out, npairs);
}

// Round 7
// 79.389 us; speedup vs baseline: 1.1268x; 1.1268x over previous
//
#include <hip/hip_runtime.h>

// Npool: soft max-pool along last axis.
// x: (8,32,64,4096) f32 -> out: (8,32,64,2047) f32, window=4, stride=2, nn=1.
// Per window: mi = first-argmax. mi in {0,3} -> out = max (eff=0).
//             mi in {1,2} -> out = 0.25*win[mi-1] + 0.5*win[mi] + 0.25*win[mi+1].
//
// R7 = R4 (block-per-row, dense float4 loads + shfl, all loads up front)
// with ONE change: nontemporal STORES. The 128 MiB write stream is never
// re-read; nt (no-allocate) keeps it from evicting the ~L3-resident input
// (256 MiB ~ Infinity Cache size) across graph replays. Loads stay plain
// so the read stream allocates in L2/L3.

#define ROW_W 4096
#define OUT_W 2047

__device__ __forceinline__ float pool4(float w0, float w1, float w2, float w3) {
    int mi = 0; float m = w0;
    if (w1 > m) { m = w1; mi = 1; }
    if (w2 > m) { m = w2; mi = 2; }
    if (w3 > m) { m = w3; mi = 3; }
    const float lo = (mi == 1) ? w0 : w1;
    const float hi = (mi == 1) ? w2 : w3;
    const float interior = 0.25f * lo + 0.5f * m + 0.25f * hi;
    return (mi == 0 || mi == 3) ? m : interior;
}

__global__ __launch_bounds__(256) void npool_kernel(const float* __restrict__ x,
                                                    float* __restrict__ out) {
    const int tid  = threadIdx.x;
    const int lane = tid & 63;
    const int wave = tid >> 6;
    const int row  = blockIdx.x;
    const float* rx = x + (size_t)row * ROW_W;
    float*       ro = out + (size_t)row * OUT_W;

    const int s0 = 4 * wave;            // this wave's first segment (of 16/row)

    // Phase 1: all loads up front (4 dense float4s/thread in flight).
    float4 v[4];
    #pragma unroll
    for (int t = 0; t < 4; ++t)
        v[t] = *reinterpret_cast<const float4*>(rx + 256 * (s0 + t) + 4 * lane);

    float2 e[4];
    if (lane == 63) {
        #pragma unroll
        for (int t = 0; t < 4; ++t) {
            int eb = 256 * (s0 + t) + 256;
            if (eb > ROW_W - 2) eb = ROW_W - 2;   // clamp: only segment 15 (value unused)
            e[t] = *reinterpret_cast<const float2*>(rx + eb);
        }
    }

    // Phase 2: share, compute, nontemporal store.
    #pragma unroll
    for (int t = 0; t < 4; ++t) {
        float n0 = __shfl_down(v[t].x, 1, 64);
        float n1 = __shfl_down(v[t].y, 1, 64);
        if (lane == 63) { n0 = e[t].x; n1 = e[t].y; }

        const float r0 = pool4(v[t].x, v[t].y, v[t].z, v[t].w);   // o = 128s+2i
        const float r1 = pool4(v[t].z, v[t].w, n0, n1);           // o = 128s+2i+1

        const int o = 128 * (s0 + t) + 2 * lane;
        __builtin_nontemporal_store(r0, ro + o);
        if (o + 1 < OUT_W)                        // masked only at s=15, lane=63
            __builtin_nontemporal_store(r1, ro + o + 1);
    }
}

extern "C" void kernel_launch(void* const* d_in, const int* in_sizes, int n_in,
                              void* d_out, int out_size, void* d_ws, size_t ws_size,
                              hipStream_t stream) {
    const float* x = (const float*)d_in[0];
    float* out = (float*)d_out;

    const int rows = in_sizes[0] / ROW_W;   // 8*32*64 = 16384
    npool_kernel<<<rows, 256, 0, stream>>>(x, out);
}

// Round 8
// 62.123 us; speedup vs baseline: 1.4399x; 1.2779x over previous
//
#include <hip/hip_runtime.h>

// Npool: soft max-pool along last axis.
// x: (8,32,64,4096) f32 -> out: (8,32,64,2047) f32, window=4, stride=2, nn=1.
// Per window: mi = first-argmax. mi in {0,3} -> out = max (eff=0).
//             mi in {1,2} -> out = 0.25*win[mi-1] + 0.5*win[mi] + 0.25*win[mi+1].
//
// R8: flat-output groups of 4 -> ALWAYS-16B-aligned float4 NT stores
// (full-line, no write amplification, no L2/L3 allocation -> input stays
// L3-resident; R7 showed 1.57x amplification from scalar NT stores and
// FETCH already at 134MB = half-resident input). Loads stay PLAIN
// (allocate read stream in L2/L3). Wave = 256 contiguous groups; lane =
// 4 adjacent outputs via 4x float2 (8B-aligned ok); tail pair from next
// lane via shfl_down. Lanes with o0 >= 2043 (straddle or shfl-tail-crosses
// -row) take a rare per-element recompute path (~0.2% of lanes).

#define ROW_W 4096
#define OUT_W 2047u

typedef float fvec4 __attribute__((ext_vector_type(4)));

__device__ __forceinline__ float pool4(float w0, float w1, float w2, float w3) {
    int mi = 0; float m = w0;
    if (w1 > m) { m = w1; mi = 1; }
    if (w2 > m) { m = w2; mi = 2; }
    if (w3 > m) { m = w3; mi = 3; }
    const float lo = (mi == 1) ? w0 : w1;
    const float hi = (mi == 1) ? w2 : w3;
    const float interior = 0.25f * lo + 0.5f * m + 0.25f * hi;
    return (mi == 0 || mi == 3) ? m : interior;
}

__global__ __launch_bounds__(256) void npool_kernel(const float* __restrict__ x,
                                                    float* __restrict__ out) {
    const int tid  = threadIdx.x;
    const int lane = tid & 63;
    const int wave = tid >> 6;
    const unsigned gw0 = blockIdx.x * 1024u + (unsigned)wave * 256u; // wave's first group

    float2 c[4][4];        // per-iteration 4x float2 = inputs x[2o0 .. 2o0+7]
    float2 tl[4];          // lane-63 tail pair
    unsigned fo[4], o0[4];

    // Phase 1: all address math + all loads issued up front (16 x 8B in flight).
    #pragma unroll
    for (int it = 0; it < 4; ++it) {
        const unsigned g = gw0 + (unsigned)(it * 64 + lane);
        fo[it] = 4u * g;
        const unsigned row = fo[it] / OUT_W;            // magic-mul division
        o0[it] = fo[it] - row * OUT_W;
        const float* p = x + (size_t)row * ROW_W + 2u * o0[it];
        c[it][0] = *reinterpret_cast<const float2*>(p);
        c[it][1] = *reinterpret_cast<const float2*>(p + 2);
        c[it][2] = *reinterpret_cast<const float2*>(p + 4);
        c[it][3] = *reinterpret_cast<const float2*>(p + 6);
        if (lane == 63)
            tl[it] = *reinterpret_cast<const float2*>(p + 8);   // in-bounds: o0<=2046 -> 2o0+9<=4101 < row+1 end; last row o0<=2043
    }

    // Phase 2: shfl tail, compute, aligned NT float4 store.
    #pragma unroll
    for (int it = 0; it < 4; ++it) {
        float t0 = __shfl_down(c[it][0].x, 1, 64);
        float t1 = __shfl_down(c[it][0].y, 1, 64);
        if (lane == 63) { t0 = tl[it].x; t1 = tl[it].y; }

        const float s0 = c[it][0].x, s1 = c[it][0].y, s2 = c[it][1].x, s3 = c[it][1].y;
        const float s4 = c[it][2].x, s5 = c[it][2].y, s6 = c[it][3].x, s7 = c[it][3].y;

        fvec4 r;
        r.x = pool4(s0, s1, s2, s3);
        r.y = pool4(s2, s3, s4, s5);
        r.z = pool4(s4, s5, s6, s7);
        r.w = pool4(s6, s7, t0, t1);

        if (o0[it] > 2042u) {      // straddle or shfl-tail-crossed-row: recompute (~0.2%)
            float rr[4];
            #pragma unroll
            for (int i = 0; i < 4; ++i) {
                const unsigned fi = fo[it] + (unsigned)i;
                const unsigned ri = fi / OUT_W;
                const unsigned oi = fi - ri * OUT_W;
                const float* q = x + (size_t)ri * ROW_W + 2u * oi;
                const float2 d0 = *reinterpret_cast<const float2*>(q);
                const float2 d1 = *reinterpret_cast<const float2*>(q + 2);
                rr[i] = pool4(d0.x, d0.y, d1.x, d1.y);
            }
            r.x = rr[0]; r.y = rr[1]; r.z = rr[2]; r.w = rr[3];
        }

        __builtin_nontemporal_store(r, reinterpret_cast<fvec4*>(out + fo[it]));
    }
}

extern "C" void kernel_launch(void* const* d_in, const int* in_sizes, int n_in,
                              void* d_out, int out_size, void* d_ws, size_t ws_size,
                              hipStream_t stream) {
    const float* x = (const float*)d_in[0];
    float* out = (float*)d_out;

    const int rows = in_sizes[0] / ROW_W;                  // 16384
    const unsigned groups = (unsigned)rows * OUT_W / 4u;   // 8,384,512
    const unsigned blocks = groups / 1024u;                // 8188 (exact)
    npool_kernel<<<blocks, 256, 0, stream>>>(x, out);
}

// Round 9
// 61.808 us; speedup vs baseline: 1.4473x; 1.0051x over previous
//
#include <hip/hip_runtime.h>

// Npool: soft max-pool along last axis.
// x: (8,32,64,4096) f32 -> out: (8,32,64,2047) f32, window=4, stride=2, nn=1.
// Per window: mi = first-argmax. mi in {0,3} -> out = max (eff=0).
//             mi in {1,2} -> out = 0.25*win[mi-1] + 0.5*win[mi] + 0.25*win[mi+1].
//
// R9 = R8 (flat groups of 4, aligned NT float4 stores, plain loads) with the
// load side rebuilt: o0 parity == row parity, so q = (2*o0) & ~3 is 16B-
// aligned; THREE aligned float4 loads cover x[q..q+11] which contains the 10
// needed inputs for both parities. Window selected via 10 cndmasks (odd =
// row&1). No shuffles, no lane-63 cases. 4 VMEM instr / 4 outputs (was 5),
// 48 L1 line-touches/iter (was 64).
// Bounds: even-row f1/f2 may read <=16B into the NEXT row (always exists:
// last row is odd); f2 clamped to row end (distorted lanes are o0>2042,
// which take the slow recompute path).

#define ROW_W 4096
#define OUT_W 2047u

typedef float fvec4 __attribute__((ext_vector_type(4)));

__device__ __forceinline__ float pool4(float w0, float w1, float w2, float w3) {
    int mi = 0; float m = w0;
    if (w1 > m) { m = w1; mi = 1; }
    if (w2 > m) { m = w2; mi = 2; }
    if (w3 > m) { m = w3; mi = 3; }
    const float lo = (mi == 1) ? w0 : w1;
    const float hi = (mi == 1) ? w2 : w3;
    const float interior = 0.25f * lo + 0.5f * m + 0.25f * hi;
    return (mi == 0 || mi == 3) ? m : interior;
}

__global__ __launch_bounds__(256) void npool_kernel(const float* __restrict__ x,
                                                    float* __restrict__ out) {
    const unsigned tid  = threadIdx.x;
    const unsigned lane = tid & 63u;
    const unsigned gw0  = blockIdx.x * 1024u + (tid >> 6) * 256u;  // wave's first group

    unsigned fo[4], o0[4], odd[4];
    fvec4 f0[4], f1[4], f2[4];

    // Phase 1: address math + 12 aligned float4 loads issued up front.
    #pragma unroll
    for (int it = 0; it < 4; ++it) {
        const unsigned g = gw0 + (unsigned)it * 64u + lane;
        fo[it] = 4u * g;
        const unsigned row = fo[it] / OUT_W;          // magic-mul division
        o0[it] = fo[it] - row * OUT_W;
        odd[it] = row & 1u;
        const float* rb = x + (size_t)row * ROW_W;
        const unsigned q = (2u * o0[it]) & ~3u;       // 16B-aligned base
        unsigned q2 = q + 8u;
        if (q2 > ROW_W - 4u) q2 = ROW_W - 4u;         // clamp (only slow-path lanes distorted)
        f0[it] = *reinterpret_cast<const fvec4*>(rb + q);
        f1[it] = *reinterpret_cast<const fvec4*>(rb + q + 4u);
        f2[it] = *reinterpret_cast<const fvec4*>(rb + q2);
    }

    // Phase 2: parity-select window, compute, aligned NT float4 store.
    #pragma unroll
    for (int it = 0; it < 4; ++it) {
        const bool od = odd[it] != 0u;
        const float s0 = od ? f0[it].z : f0[it].x;
        const float s1 = od ? f0[it].w : f0[it].y;
        const float s2 = od ? f1[it].x : f0[it].z;
        const float s3 = od ? f1[it].y : f0[it].w;
        const float s4 = od ? f1[it].z : f1[it].x;
        const float s5 = od ? f1[it].w : f1[it].y;
        const float s6 = od ? f2[it].x : f1[it].z;
        const float s7 = od ? f2[it].y : f1[it].w;
        const float t0 = od ? f2[it].z : f2[it].x;
        const float t1 = od ? f2[it].w : f2[it].y;

        fvec4 r;
        r.x = pool4(s0, s1, s2, s3);
        r.y = pool4(s2, s3, s4, s5);
        r.z = pool4(s4, s5, s6, s7);
        r.w = pool4(s6, s7, t0, t1);

        if (o0[it] > 2042u) {      // row straddle / clamped-tail lanes: recompute (~0.2%)
            float rr[4];
            #pragma unroll
            for (int i = 0; i < 4; ++i) {
                const unsigned fi = fo[it] + (unsigned)i;
                const unsigned ri = fi / OUT_W;
                const unsigned oi = fi - ri * OUT_W;
                const float* p = x + (size_t)ri * ROW_W + 2u * oi;
                const float2 d0 = *reinterpret_cast<const float2*>(p);
                const float2 d1 = *reinterpret_cast<const float2*>(p + 2);
                rr[i] = pool4(d0.x, d0.y, d1.x, d1.y);
            }
            r.x = rr[0]; r.y = rr[1]; r.z = rr[2]; r.w = rr[3];
        }

        __builtin_nontemporal_store(r, reinterpret_cast<fvec4*>(out + fo[it]));
    }
}

extern "C" void kernel_launch(void* const* d_in, const int* in_sizes, int n_in,
                              void* d_out, int out_size, void* d_ws, size_t ws_size,
                              hipStream_t stream) {
    const float* x = (const float*)d_in[0];
    float* out = (float*)d_out;

    const int rows = in_sizes[0] / ROW_W;                  // 16384
    const unsigned groups = (unsigned)rows * OUT_W / 4u;   // 8,384,512
    const unsigned blocks = groups / 1024u;                // 8188 (exact)
    npool_kernel<<<blocks, 256, 0, stream>>>(x, out);
}